// Round 5
// baseline (162.338 us; speedup 1.0000x reference)
//
#include <hip/hip_runtime.h>
#include <math.h>

// B=4, S=2048, D=512, H=8, A=O=64.
// prep: x f32 -> xh f16; W -> W^T f16.
// qkv_gemm: 128x64 tiles, grid (64 m,17 n) -> XCD = m%8 (1MB x-slice + 1.1MB W
//   L2-resident per XCD). Single-buffer 2-barrier global_load_lds staging.
// K and V^T stored as swizzled 64x64 f16 tiles (8KB):
//   (row,col) at halves offset row*64 + (((col>>3) ^ (row&7))<<3) + (col&7)
// attn: q-tile 64, 4 waves, paired q-tiles {p,31-p} -> 33 iters/block uniform;
//   grid (32 bh, 16 pair) = 512 blocks = 2 blocks/CU (two barrier domains per CU
//   so vmcnt(0) barrier drains overlap); XCD = bh%8 -> KV L2-resident.

typedef _Float16 half8 __attribute__((ext_vector_type(8)));
typedef _Float16 half4 __attribute__((ext_vector_type(4)));
typedef float float4v __attribute__((ext_vector_type(4)));
typedef unsigned int u32;

#define SCL2E 0.031885926f   // (1/sqrt(2048)) * log2(e)

__device__ inline float4v mfma16(half8 a, half8 b, float4v c) {
    return __builtin_amdgcn_mfma_f32_16x16x32_f16(a, b, c, 0, 0, 0);
}
__device__ inline void load16(const _Float16* g, _Float16* l) {
    __builtin_amdgcn_global_load_lds((const __attribute__((address_space(1))) u32*)g,
                                     (__attribute__((address_space(3))) u32*)l, 16, 0, 0);
}

// ---------------- prep: x -> f16, W -> W^T f16 (one launch) ----------------
__global__ __launch_bounds__(256) void prep(
    const float* __restrict__ x, const float* __restrict__ Wq,
    const float* __restrict__ Wk, const float* __restrict__ Wv,
    _Float16* __restrict__ xh, _Float16* __restrict__ wqt,
    _Float16* __restrict__ wkt, _Float16* __restrict__ wvt) {
    const int bid = blockIdx.x;
    if (bid < 2048) {
        size_t base = (size_t)bid * 2048 + (size_t)threadIdx.x * 8;
        const float4* xp = (const float4*)(x + base);
        float4 f0 = xp[0], f1 = xp[1];
        half8 h = {(_Float16)f0.x, (_Float16)f0.y, (_Float16)f0.z, (_Float16)f0.w,
                   (_Float16)f1.x, (_Float16)f1.y, (_Float16)f1.z, (_Float16)f1.w};
        *(half8*)(xh + base) = h;
    } else {
        int r = bid - 2048;
        const float* W; _Float16* WT; int N, bx, by;
        if (r < 256)      { W = Wq; WT = wqt; N = 512; bx = r & 15; by = r >> 4; }
        else if (r < 288) { r -= 256; W = Wk; WT = wkt; N = 64;  bx = r & 1;  by = r >> 1; }
        else              { r -= 288; W = Wv; WT = wvt; N = 512; bx = r & 15; by = r >> 4; }
        __shared__ float T[32][33];
        const int tx = threadIdx.x & 31, ty = threadIdx.x >> 5;
        const int n0 = bx * 32, k0 = by * 32;
#pragma unroll
        for (int i = 0; i < 4; ++i)
            T[ty + 8 * i][tx] = W[(size_t)(k0 + ty + 8 * i) * N + n0 + tx];
        __syncthreads();
#pragma unroll
        for (int i = 0; i < 4; ++i)
            WT[(size_t)(n0 + ty + 8 * i) * 512 + k0 + tx] = (_Float16)T[tx][ty + 8 * i];
    }
}

// ---------------- fused QKV GEMM ----------------
// grid (64, 17): x = m-tile (128 rows) -> XCD = m%8; y = n-tile (0..7 q, 8 k, 9..16 v).
__global__ __launch_bounds__(256) void qkv_gemm(
    const _Float16* __restrict__ xh,
    const _Float16* __restrict__ wqt, const _Float16* __restrict__ wkt,
    const _Float16* __restrict__ wvt,
    const float* __restrict__ bq, const float* __restrict__ bv,
    _Float16* __restrict__ q_ws, _Float16* __restrict__ kt_ws, _Float16* __restrict__ vt_ws) {
    __shared__ __align__(16) _Float16 Xs[8192];   // 128 x 64 (swizzled)
    __shared__ __align__(16) _Float16 Ws[4096];   // 64 x 64 (swizzled)

    const int m0 = blockIdx.x * 128;
    const int nt = blockIdx.y;
    const _Float16* WT;
    const float* bias;
    if (nt < 8)       { WT = wqt + (size_t)nt * 64 * 512; bias = bq + nt * 64; }
    else if (nt == 8) { WT = wkt;                          bias = nullptr; }
    else              { WT = wvt + (size_t)(nt - 9) * 64 * 512; bias = bv + (nt - 9) * 64; }

    const int tid = threadIdx.x;
    const int w = tid >> 6, lane = tid & 63, quad = lane >> 4, cl = lane & 15;
    const int lrow = lane >> 3;                  // 0..7
    const int lgc = (lane & 7) ^ lrow;           // swizzled source granule
    const _Float16* xg = xh + (size_t)(m0 + lrow) * 512 + lgc * 8;
    const _Float16* wg = WT + (size_t)lrow * 512 + lgc * 8;

    const int g0 = (quad ^ (cl & 7)) << 3;
    const int g1 = ((quad ^ 4) ^ (cl & 7)) << 3;

    float4v acc[2][4] = {};

    for (int ki = 0; ki < 8; ++ki) {
        const int kk = ki * 64;
        __syncthreads();   // everyone done reading previous tile
#pragma unroll
        for (int c = 0; c < 4; ++c) {            // X: 16 chunks of 8 rows
            int cc = w * 4 + c;
            load16(xg + (size_t)cc * 8 * 512 + kk, Xs + cc * 512);
        }
#pragma unroll
        for (int c = 0; c < 2; ++c) {            // W: 8 chunks
            int cc = w * 2 + c;
            load16(wg + (size_t)cc * 8 * 512 + kk, Ws + cc * 512);
        }
        __syncthreads();   // vmcnt(0) drain -> tile ready
#pragma unroll
        for (int c = 0; c < 2; ++c) {
            const int g = c ? g1 : g0;
#pragma unroll
            for (int s = 0; s < 2; ++s) {
                half8 a = *(const half8*)(Xs + (w * 32 + s * 16 + cl) * 64 + g);
#pragma unroll
                for (int j = 0; j < 4; ++j) {
                    half8 b = *(const half8*)(Ws + (j * 16 + cl) * 64 + g);
                    acc[s][j] = mfma16(a, b, acc[s][j]);
                }
            }
        }
    }

    if (nt < 8) {
#pragma unroll
        for (int s = 0; s < 2; ++s)
#pragma unroll
            for (int j = 0; j < 4; ++j)
#pragma unroll
                for (int r = 0; r < 4; ++r) {
                    int lr = w * 32 + s * 16 + quad * 4 + r;
                    int col = j * 16 + cl;
                    q_ws[(size_t)(m0 + lr) * 512 + nt * 64 + col] =
                        (_Float16)((acc[s][j][r] + bias[col]) * SCL2E);
                }
    } else if (nt == 8) {
#pragma unroll
        for (int s = 0; s < 2; ++s)
#pragma unroll
            for (int j = 0; j < 4; ++j)
#pragma unroll
                for (int r = 0; r < 4; ++r) {
                    int grow = m0 + w * 32 + s * 16 + quad * 4 + r;
                    int b = grow >> 11, t = (grow >> 6) & 31, row = grow & 63;
                    int col = j * 16 + cl;
                    kt_ws[((size_t)(b * 32 + t) << 12) + row * 64 +
                          (((col >> 3) ^ (row & 7)) << 3) + (col & 7)] = (_Float16)acc[s][j][r];
                }
    } else {
        const int h = nt - 9;
#pragma unroll
        for (int s = 0; s < 2; ++s)
#pragma unroll
            for (int j = 0; j < 4; ++j)
#pragma unroll
                for (int r = 0; r < 4; ++r) {
                    int grow = m0 + w * 32 + s * 16 + quad * 4 + r;
                    int b = grow >> 11, t = (grow >> 6) & 31, row = grow & 63;
                    int o = j * 16 + cl;
                    int kap = ((row & 15) << 2) + (row >> 4);
                    vt_ws[(((size_t)(b * 8 + h) * 32 + t) << 12) + o * 64 +
                          (((kap >> 3) ^ (o & 7)) << 3) + (kap & 7)] =
                        (_Float16)(acc[s][j][r] + bias[o]);
                }
    }
}

// ---------------- causal flash attention ----------------
// grid (32, 16): x = bh -> XCD = bh%8; y = pair; block does q-tiles {p, 31-p} (64 rows).
// 256 threads = 4 waves; wave w owns 16 q rows. 33 KV-iters/block uniform; 2 blocks/CU.
__global__ __launch_bounds__(256) void attn(
    const _Float16* __restrict__ q_ws, const _Float16* __restrict__ kt_ws,
    const _Float16* __restrict__ vt_ws, float* __restrict__ out) {
    __shared__ __align__(16) _Float16 Ks[4096];
    __shared__ __align__(16) _Float16 VTs[2][4096];
    __shared__ __align__(16) _Float16 Ps[4][1024];

    const int bh = blockIdx.x, b = bh >> 3, h = bh & 7;
    const int pair = blockIdx.y;
    const int bS = b * 2048;
    const int tid = threadIdx.x;
    const int w = tid >> 6, lane = tid & 63, quad = lane >> 4, cl = lane & 15;

    const _Float16* kbase = kt_ws + ((size_t)(b * 32) << 12);
    const _Float16* vbase = vt_ws + ((size_t)((b * 8 + h) * 32) << 12);

    const int g0 = (quad ^ (cl & 7)) << 3;
    const int g1 = ((quad ^ 4) ^ (cl & 7)) << 3;
    const int soff = w * 1024 + lane * 8;

    for (int phase = 0; phase < 2; ++phase) {
        const int qt = phase ? (31 - pair) : pair;
        const int tlast = qt;
        const int q0 = qt * 64;

        // Q pre-scaled by SCL2E in gemm epilogue
        const _Float16* qbase = q_ws + (size_t)(bS + q0 + w * 16 + cl) * 512 + h * 64;
        half8 qa0 = *(const half8*)(qbase + quad * 8);
        half8 qa1 = *(const half8*)(qbase + 32 + quad * 8);

        float4v oacc[4] = {};
        float l_run[4] = {0.f, 0.f, 0.f, 0.f};

        // all waves done reading prior phase's Ks/VTs before reuse
        __syncthreads();
        load16(kbase + soff,       &Ks[w * 1024]);
        load16(kbase + soff + 512, &Ks[w * 1024 + 512]);
        load16(vbase + soff,       &VTs[0][w * 1024]);
        load16(vbase + soff + 512, &VTs[0][w * 1024 + 512]);

        for (int t = 0; t <= tlast; ++t) {
            __syncthreads();   // bar1: K[t]/V[t] arrived; all waves done PV[t-1]
            if (t < tlast) {   // V[t+1] -> other V buffer; overlaps QK+softmax
                const _Float16* vg = vbase + ((size_t)(t + 1) << 12);
                const int nb = (t + 1) & 1;
                load16(vg + soff,       &VTs[nb][w * 1024]);
                load16(vg + soff + 512, &VTs[nb][w * 1024 + 512]);
            }
            const bool diag = (t == tlast);
            const int jmax = diag ? w : 3;   // wave-uniform

            float4v sfr[4];
#pragma unroll
            for (int j = 0; j < 4; ++j) {
                if (j <= jmax) {
                    const _Float16* kr = &Ks[(j * 16 + cl) * 64];
                    half8 b0 = *(const half8*)(kr + g0);
                    half8 b1 = *(const half8*)(kr + g1);
                    float4v a_ = {0.f, 0.f, 0.f, 0.f};
                    a_ = mfma16(qa0, b0, a_);
                    a_ = mfma16(qa1, b1, a_);
                    sfr[j] = a_;
                }
            }
#pragma unroll
            for (int r = 0; r < 4; ++r) {
                float pj[4];
#pragma unroll
                for (int j = 0; j < 4; ++j) {
                    bool live = (j < jmax) || ((j == jmax) && (!diag || cl <= quad * 4 + r));
                    pj[j] = live ? exp2f(sfr[j][r]) : 0.f;
                }
                l_run[r] += (pj[0] + pj[1]) + (pj[2] + pj[3]);
                int rr = quad * 4 + r;
                half4 ph = {(_Float16)pj[0], (_Float16)pj[1], (_Float16)pj[2], (_Float16)pj[3]};
                *(half4*)&Ps[w][rr * 64 + ((((cl >> 1) ^ (rr & 7)) << 3) | ((cl & 1) << 2))] = ph;
            }
            __syncthreads();   // bar2: Ks fully consumed
            if (t < tlast) {   // K[t+1] -> Ks; overlaps P-read + PV
                const _Float16* kg = kbase + ((size_t)(t + 1) << 12);
                load16(kg + soff,       &Ks[w * 1024]);
                load16(kg + soff + 512, &Ks[w * 1024 + 512]);
            }
            // PV: A = P (kappa-space), B = VT (kappa-space)
            const _Float16* PB = &Ps[w][cl * 64];
            half8 pa0 = *(const half8*)(PB + g0);
            half8 pa1 = *(const half8*)(PB + g1);
            const int bb = t & 1;
#pragma unroll
            for (int jo = 0; jo < 4; ++jo) {
                const _Float16* vr = &VTs[bb][(jo * 16 + cl) * 64];
                half8 v0 = *(const half8*)(vr + g0);
                half8 v1 = *(const half8*)(vr + g1);
                oacc[jo] = mfma16(pa0, v0, oacc[jo]);
                oacc[jo] = mfma16(pa1, v1, oacc[jo]);
            }
        }
        // epilogue for this q-tile (registers + shuffles only; no LDS)
#pragma unroll
        for (int r = 0; r < 4; ++r) {
            float l = l_run[r];
            l += __shfl_xor(l, 1);
            l += __shfl_xor(l, 2);
            l += __shfl_xor(l, 4);
            l += __shfl_xor(l, 8);
            float inv = 1.0f / l;
            int row = q0 + w * 16 + quad * 4 + r;
            float* op = out + (size_t)(bS + row) * 512 + h * 64 + cl;
            op[0]  = oacc[0][r] * inv;
            op[16] = oacc[1][r] * inv;
            op[32] = oacc[2][r] * inv;
            op[48] = oacc[3][r] * inv;
        }
    }
}

extern "C" void kernel_launch(void* const* d_in, const int* in_sizes, int n_in,
                              void* d_out, int out_size, void* d_ws, size_t ws_size,
                              hipStream_t stream) {
    const float* x  = (const float*)d_in[0];
    const float* Wq = (const float*)d_in[1];
    const float* bq = (const float*)d_in[2];
    const float* Wk = (const float*)d_in[3];
    const float* Wv = (const float*)d_in[4];
    const float* bv = (const float*)d_in[5];
    float* out = (float*)d_out;

    char* ws = (char*)d_ws;
    _Float16* q_ws  = (_Float16*)(ws);                 // 8192*512*2     = 8388608
    _Float16* kt_ws = (_Float16*)(ws + 8388608);       // 4*32*4096*2    = 1048576
    _Float16* vt_ws = (_Float16*)(ws + 9437184);       // 4*8*32*4096*2  = 8388608
    _Float16* wqt   = (_Float16*)(ws + 17825792);      // 512*512*2      = 524288
    _Float16* wkt   = (_Float16*)(ws + 18350080);      // 64*512*2       = 65536
    _Float16* wvt   = (_Float16*)(ws + 18415616);      // 512*512*2      = 524288
    _Float16* xh    = (_Float16*)(ws + 18939904);      // 8192*512*2     = 8388608 -> end 27328512

    prep<<<dim3(2592), dim3(256), 0, stream>>>(x, Wq, Wk, Wv, xh, wqt, wkt, wvt);

    qkv_gemm<<<dim3(64, 17), dim3(256), 0, stream>>>(
        xh, wqt, wkt, wvt, bq, bv, q_ws, kt_ws, vt_ws);

    attn<<<dim3(32, 16), dim3(256), 0, stream>>>(q_ws, kt_ws, vt_ws, out);
}

// Round 6
// 152.472 us; speedup vs baseline: 1.0647x; 1.0647x over previous
//
#include <hip/hip_runtime.h>
#include <math.h>

// B=4, S=2048, D=512, H=8, A=O=64.
// prep: x f32 -> xh f16; W -> W^T f16.
// qkv_gemm: 128x64 tiles, grid (64 m,17 n) -> XCD = m%8 (1MB x-slice + 1.1MB W
//   L2-resident per XCD). Single-buffer 2-barrier global_load_lds staging.
// K and V^T stored as swizzled 64x64 f16 tiles (8KB):
//   (row,col) at halves offset row*64 + (((col>>3) ^ (row&7))<<3) + (col&7)
// attn: q-tile 128 (8 waves), paired q-tiles {y,15-y} -> 34 iters/block uniform;
//   grid (32 bh, 8) = 256 blocks = 1/CU; XCD = bh%8 -> KV L2-resident.
//   K AND V double-buffered, ONE barrier/iter: the vmcnt(0) drain at iter t's
//   barrier waits on loads issued at iter t-1's barrier (full-iter overlap).

typedef _Float16 half8 __attribute__((ext_vector_type(8)));
typedef _Float16 half4 __attribute__((ext_vector_type(4)));
typedef float float4v __attribute__((ext_vector_type(4)));
typedef unsigned int u32;

#define SCL2E 0.031885926f   // (1/sqrt(2048)) * log2(e)

__device__ inline float4v mfma16(half8 a, half8 b, float4v c) {
    return __builtin_amdgcn_mfma_f32_16x16x32_f16(a, b, c, 0, 0, 0);
}
__device__ inline void load16(const _Float16* g, _Float16* l) {
    __builtin_amdgcn_global_load_lds((const __attribute__((address_space(1))) u32*)g,
                                     (__attribute__((address_space(3))) u32*)l, 16, 0, 0);
}

// ---------------- prep: x -> f16, W -> W^T f16 (one launch) ----------------
__global__ __launch_bounds__(256) void prep(
    const float* __restrict__ x, const float* __restrict__ Wq,
    const float* __restrict__ Wk, const float* __restrict__ Wv,
    _Float16* __restrict__ xh, _Float16* __restrict__ wqt,
    _Float16* __restrict__ wkt, _Float16* __restrict__ wvt) {
    const int bid = blockIdx.x;
    if (bid < 2048) {
        size_t base = (size_t)bid * 2048 + (size_t)threadIdx.x * 8;
        const float4* xp = (const float4*)(x + base);
        float4 f0 = xp[0], f1 = xp[1];
        half8 h = {(_Float16)f0.x, (_Float16)f0.y, (_Float16)f0.z, (_Float16)f0.w,
                   (_Float16)f1.x, (_Float16)f1.y, (_Float16)f1.z, (_Float16)f1.w};
        *(half8*)(xh + base) = h;
    } else {
        int r = bid - 2048;
        const float* W; _Float16* WT; int N, bx, by;
        if (r < 256)      { W = Wq; WT = wqt; N = 512; bx = r & 15; by = r >> 4; }
        else if (r < 288) { r -= 256; W = Wk; WT = wkt; N = 64;  bx = r & 1;  by = r >> 1; }
        else              { r -= 288; W = Wv; WT = wvt; N = 512; bx = r & 15; by = r >> 4; }
        __shared__ float T[32][33];
        const int tx = threadIdx.x & 31, ty = threadIdx.x >> 5;
        const int n0 = bx * 32, k0 = by * 32;
#pragma unroll
        for (int i = 0; i < 4; ++i)
            T[ty + 8 * i][tx] = W[(size_t)(k0 + ty + 8 * i) * N + n0 + tx];
        __syncthreads();
#pragma unroll
        for (int i = 0; i < 4; ++i)
            WT[(size_t)(n0 + ty + 8 * i) * 512 + k0 + tx] = (_Float16)T[tx][ty + 8 * i];
    }
}

// ---------------- fused QKV GEMM ----------------
// grid (64, 17): x = m-tile (128 rows) -> XCD = m%8; y = n-tile (0..7 q, 8 k, 9..16 v).
__global__ __launch_bounds__(256) void qkv_gemm(
    const _Float16* __restrict__ xh,
    const _Float16* __restrict__ wqt, const _Float16* __restrict__ wkt,
    const _Float16* __restrict__ wvt,
    const float* __restrict__ bq, const float* __restrict__ bv,
    _Float16* __restrict__ q_ws, _Float16* __restrict__ kt_ws, _Float16* __restrict__ vt_ws) {
    __shared__ __align__(16) _Float16 Xs[8192];   // 128 x 64 (swizzled)
    __shared__ __align__(16) _Float16 Ws[4096];   // 64 x 64 (swizzled)

    const int m0 = blockIdx.x * 128;
    const int nt = blockIdx.y;
    const _Float16* WT;
    const float* bias;
    if (nt < 8)       { WT = wqt + (size_t)nt * 64 * 512; bias = bq + nt * 64; }
    else if (nt == 8) { WT = wkt;                          bias = nullptr; }
    else              { WT = wvt + (size_t)(nt - 9) * 64 * 512; bias = bv + (nt - 9) * 64; }

    const int tid = threadIdx.x;
    const int w = tid >> 6, lane = tid & 63, quad = lane >> 4, cl = lane & 15;
    const int lrow = lane >> 3;                  // 0..7
    const int lgc = (lane & 7) ^ lrow;           // swizzled source granule
    const _Float16* xg = xh + (size_t)(m0 + lrow) * 512 + lgc * 8;
    const _Float16* wg = WT + (size_t)lrow * 512 + lgc * 8;

    const int g0 = (quad ^ (cl & 7)) << 3;
    const int g1 = ((quad ^ 4) ^ (cl & 7)) << 3;

    float4v acc[2][4] = {};

    for (int ki = 0; ki < 8; ++ki) {
        const int kk = ki * 64;
        __syncthreads();   // everyone done reading previous tile
#pragma unroll
        for (int c = 0; c < 4; ++c) {            // X: 16 chunks of 8 rows
            int cc = w * 4 + c;
            load16(xg + (size_t)cc * 8 * 512 + kk, Xs + cc * 512);
        }
#pragma unroll
        for (int c = 0; c < 2; ++c) {            // W: 8 chunks
            int cc = w * 2 + c;
            load16(wg + (size_t)cc * 8 * 512 + kk, Ws + cc * 512);
        }
        __syncthreads();   // vmcnt(0) drain -> tile ready
#pragma unroll
        for (int c = 0; c < 2; ++c) {
            const int g = c ? g1 : g0;
#pragma unroll
            for (int s = 0; s < 2; ++s) {
                half8 a = *(const half8*)(Xs + (w * 32 + s * 16 + cl) * 64 + g);
#pragma unroll
                for (int j = 0; j < 4; ++j) {
                    half8 b = *(const half8*)(Ws + (j * 16 + cl) * 64 + g);
                    acc[s][j] = mfma16(a, b, acc[s][j]);
                }
            }
        }
    }

    if (nt < 8) {
#pragma unroll
        for (int s = 0; s < 2; ++s)
#pragma unroll
            for (int j = 0; j < 4; ++j)
#pragma unroll
                for (int r = 0; r < 4; ++r) {
                    int lr = w * 32 + s * 16 + quad * 4 + r;
                    int col = j * 16 + cl;
                    q_ws[(size_t)(m0 + lr) * 512 + nt * 64 + col] =
                        (_Float16)((acc[s][j][r] + bias[col]) * SCL2E);
                }
    } else if (nt == 8) {
#pragma unroll
        for (int s = 0; s < 2; ++s)
#pragma unroll
            for (int j = 0; j < 4; ++j)
#pragma unroll
                for (int r = 0; r < 4; ++r) {
                    int grow = m0 + w * 32 + s * 16 + quad * 4 + r;
                    int b = grow >> 11, t = (grow >> 6) & 31, row = grow & 63;
                    int col = j * 16 + cl;
                    kt_ws[((size_t)(b * 32 + t) << 12) + row * 64 +
                          (((col >> 3) ^ (row & 7)) << 3) + (col & 7)] = (_Float16)acc[s][j][r];
                }
    } else {
        const int h = nt - 9;
#pragma unroll
        for (int s = 0; s < 2; ++s)
#pragma unroll
            for (int j = 0; j < 4; ++j)
#pragma unroll
                for (int r = 0; r < 4; ++r) {
                    int grow = m0 + w * 32 + s * 16 + quad * 4 + r;
                    int b = grow >> 11, t = (grow >> 6) & 31, row = grow & 63;
                    int o = j * 16 + cl;
                    int kap = ((row & 15) << 2) + (row >> 4);
                    vt_ws[(((size_t)(b * 8 + h) * 32 + t) << 12) + o * 64 +
                          (((kap >> 3) ^ (o & 7)) << 3) + (kap & 7)] =
                        (_Float16)(acc[s][j][r] + bias[o]);
                }
    }
}

// ---------------- causal flash attention ----------------
// grid (32, 8): x = bh -> XCD = bh%8; y = pair; block does q-tiles {y, 15-y} (128 rows).
// 512 threads = 8 waves; wave w owns 16 q rows. 34 KV-iters/block uniform.
// K+V both double-buffered; ONE barrier per iter -> full-iter load overlap.
__global__ __launch_bounds__(512) void attn(
    const _Float16* __restrict__ q_ws, const _Float16* __restrict__ kt_ws,
    const _Float16* __restrict__ vt_ws, float* __restrict__ out) {
    __shared__ __align__(16) _Float16 Ks[2][4096];
    __shared__ __align__(16) _Float16 VTs[2][4096];
    __shared__ __align__(16) _Float16 Ps[8][1024];

    const int bh = blockIdx.x, b = bh >> 3, h = bh & 7;
    const int pair = blockIdx.y;
    const int bS = b * 2048;
    const int tid = threadIdx.x;
    const int w = tid >> 6, lane = tid & 63, quad = lane >> 4, cl = lane & 15;

    const _Float16* kbase = kt_ws + ((size_t)(b * 32) << 12);
    const _Float16* vbase = vt_ws + ((size_t)((b * 8 + h) * 32) << 12);

    const int g0 = (quad ^ (cl & 7)) << 3;
    const int g1 = ((quad ^ 4) ^ (cl & 7)) << 3;
    const int soff = w * 512 + lane * 8;   // 8 waves x 512 halves = one 64x64 tile

    for (int phase = 0; phase < 2; ++phase) {
        const int qt = phase ? (15 - pair) : pair;
        const int tlast = 2 * qt + 1;
        const int q0 = qt * 128;

        // Q pre-scaled by SCL2E in gemm epilogue
        const _Float16* qbase = q_ws + (size_t)(bS + q0 + w * 16 + cl) * 512 + h * 64;
        half8 qa0 = *(const half8*)(qbase + quad * 8);
        half8 qa1 = *(const half8*)(qbase + 32 + quad * 8);

        float4v oacc[4] = {};
        float l_run[4] = {0.f, 0.f, 0.f, 0.f};

        __syncthreads();   // prior phase fully done with all buffers
        load16(kbase + soff, &Ks[0][soff]);
        load16(vbase + soff, &VTs[0][soff]);

        for (int t = 0; t <= tlast; ++t) {
            __syncthreads();   // drains K/V[t] (issued one full iter ago); iter t-1 compute done
            if (t < tlast) {   // K/V[t+1] -> other buffers; consumed at next barrier
                const size_t off = (size_t)(t + 1) << 12;
                const int nb = (t + 1) & 1;
                load16(kbase + off + soff, &Ks[nb][soff]);
                load16(vbase + off + soff, &VTs[nb][soff]);
            }
            const int bb = t & 1;
            // ww: 100 = full tile; 0..3 = diagonal sub-block index; <0 = fully masked
            const int ww = (t == tlast) ? (w - 4) : ((t == 2 * qt) ? w : 100);
            if (ww >= 0) {
                const int jmax = ww < 3 ? ww : 3;
                float4v sfr[4];
#pragma unroll
                for (int j = 0; j < 4; ++j) {
                    if (j <= jmax) {
                        const _Float16* kr = &Ks[bb][(j * 16 + cl) * 64];
                        half8 b0 = *(const half8*)(kr + g0);
                        half8 b1 = *(const half8*)(kr + g1);
                        float4v a_ = {0.f, 0.f, 0.f, 0.f};
                        a_ = mfma16(qa0, b0, a_);
                        a_ = mfma16(qa1, b1, a_);
                        sfr[j] = a_;
                    }
                }
#pragma unroll
                for (int r = 0; r < 4; ++r) {
                    float pj[4];
#pragma unroll
                    for (int j = 0; j < 4; ++j) {
                        bool live = (j < jmax) ||
                                    (j == jmax && (ww > 3 || cl <= quad * 4 + r));
                        pj[j] = live ? exp2f(sfr[j][r]) : 0.f;
                    }
                    l_run[r] += (pj[0] + pj[1]) + (pj[2] + pj[3]);
                    int rr = quad * 4 + r;
                    half4 ph = {(_Float16)pj[0], (_Float16)pj[1], (_Float16)pj[2], (_Float16)pj[3]};
                    *(half4*)&Ps[w][rr * 64 + ((((cl >> 1) ^ (rr & 7)) << 3) | ((cl & 1) << 2))] = ph;
                }
                // P strip is per-wave; DS ops in-order within a wave -> no barrier needed
                const _Float16* PB = &Ps[w][cl * 64];
                half8 pa0 = *(const half8*)(PB + g0);
                half8 pa1 = *(const half8*)(PB + g1);
#pragma unroll
                for (int jo = 0; jo < 4; ++jo) {
                    const _Float16* vr = &VTs[bb][(jo * 16 + cl) * 64];
                    half8 v0 = *(const half8*)(vr + g0);
                    half8 v1 = *(const half8*)(vr + g1);
                    oacc[jo] = mfma16(pa0, v0, oacc[jo]);
                    oacc[jo] = mfma16(pa1, v1, oacc[jo]);
                }
            }
        }
        // epilogue for this q-tile (registers + shuffles only; no LDS)
#pragma unroll
        for (int r = 0; r < 4; ++r) {
            float l = l_run[r];
            l += __shfl_xor(l, 1);
            l += __shfl_xor(l, 2);
            l += __shfl_xor(l, 4);
            l += __shfl_xor(l, 8);
            float inv = 1.0f / l;
            int row = q0 + w * 16 + quad * 4 + r;
            float* op = out + (size_t)(bS + row) * 512 + h * 64 + cl;
            op[0]  = oacc[0][r] * inv;
            op[16] = oacc[1][r] * inv;
            op[32] = oacc[2][r] * inv;
            op[48] = oacc[3][r] * inv;
        }
    }
}

extern "C" void kernel_launch(void* const* d_in, const int* in_sizes, int n_in,
                              void* d_out, int out_size, void* d_ws, size_t ws_size,
                              hipStream_t stream) {
    const float* x  = (const float*)d_in[0];
    const float* Wq = (const float*)d_in[1];
    const float* bq = (const float*)d_in[2];
    const float* Wk = (const float*)d_in[3];
    const float* Wv = (const float*)d_in[4];
    const float* bv = (const float*)d_in[5];
    float* out = (float*)d_out;

    char* ws = (char*)d_ws;
    _Float16* q_ws  = (_Float16*)(ws);                 // 8192*512*2     = 8388608
    _Float16* kt_ws = (_Float16*)(ws + 8388608);       // 4*32*4096*2    = 1048576
    _Float16* vt_ws = (_Float16*)(ws + 9437184);       // 4*8*32*4096*2  = 8388608
    _Float16* wqt   = (_Float16*)(ws + 17825792);      // 512*512*2      = 524288
    _Float16* wkt   = (_Float16*)(ws + 18350080);      // 64*512*2       = 65536
    _Float16* wvt   = (_Float16*)(ws + 18415616);      // 512*512*2      = 524288
    _Float16* xh    = (_Float16*)(ws + 18939904);      // 8192*512*2     = 8388608 -> end 27328512

    prep<<<dim3(2592), dim3(256), 0, stream>>>(x, Wq, Wk, Wv, xh, wqt, wkt, wvt);

    qkv_gemm<<<dim3(64, 17), dim3(256), 0, stream>>>(
        xh, wqt, wkt, wvt, bq, bv, q_ws, kt_ws, vt_ws);

    attn<<<dim3(32, 8), dim3(512), 0, stream>>>(q_ws, kt_ws, vt_ws, out);
}